// Round 4
// baseline (3040.677 us; speedup 1.0000x reference)
//
#include <hip/hip_runtime.h>
#include <cstddef>

// SNN: 4-layer LIF net, T=200 sequential steps, batch 4096.
// R4: (a) nontemporal x staging loads — x's t-strided line touches were
// evicting the 622 KB weight set from each XCD L2 every window (5.2 MB of
// lines/window/XCD > 4 MB L2), causing the 9.9 GB FETCH; (b) asm register
// pin forces W2hi/W3hi truly register-resident (64 VGPRs) — launch_bounds
// alone let the allocator sink the loads back into the loop (VGPR stayed
// 64). Streamed weights drop to 352 KB/step/CU, all L2-resident.
// Numerics bitwise identical to R1-R3 (absmax 0): MFMA order unchanged.
//
// ws layout (_Float16 units): W1hi[256*96] W1lo[256*96] W2hi[256*256]
// W2lo[..] W3hi[..] W3lo[..]  -> 622,592 bytes.

#define BATCH 4096
#define TSTEPS 200
#define NIN 80
#define KP 96
#define NH 256
#define XPAD 104
#define SPAD 264

#define W1HI 0
#define W1LO 24576
#define W2HI 49152
#define W2LO 114688
#define W3HI 180224
#define W3LO 245760

#define LO_SCALE 2048.0f
#define LO_INV 4.8828125e-4f

typedef _Float16 h8 __attribute__((ext_vector_type(8)));
typedef float f4 __attribute__((ext_vector_type(4)));

// LDS-only barrier: wait lgkmcnt(0), do NOT drain vmcnt.
// simm16 0xC07F: vmcnt=63 (no wait), expcnt=7 (no wait), lgkmcnt=0.
__device__ __forceinline__ void lds_barrier() {
  __builtin_amdgcn_s_waitcnt(0xC07F);
  __builtin_amdgcn_s_barrier();
}

// Register pin: value becomes an opaque asm output — cannot be
// rematerialized/sunk by the register allocator. Forces true residency.
__device__ __forceinline__ void pin4(f4& v) { asm volatile("" : "+v"(v)); }

__global__ __launch_bounds__(256) void prep_kernel(
    const float* __restrict__ W1, const float* __restrict__ W2,
    const float* __restrict__ W3, _Float16* __restrict__ ws) {
  unsigned id = blockIdx.x * 256u + threadIdx.x;
  if (id >= 24576u + 65536u + 65536u) return;
  float v;
  unsigned off;
  _Float16 *hi, *lo;
  if (id < 24576u) {
    unsigned n = id / KP, k = id % KP;
    v = (k < NIN) ? W1[n * NIN + k] : 0.0f;
    hi = ws + W1HI; lo = ws + W1LO; off = id;
  } else if (id < 90112u) {
    off = id - 24576u; v = W2[off];
    hi = ws + W2HI; lo = ws + W2LO;
  } else {
    off = id - 90112u; v = W3[off];
    hi = ws + W3HI; lo = ws + W3LO;
  }
  _Float16 h = (_Float16)v;
  float r = (v - (float)h) * LO_SCALE;
  hi[off] = h;
  lo[off] = (_Float16)r;
}

__global__ __launch_bounds__(1024, 4) void snn_kernel(
    const float* __restrict__ x,
    const float* __restrict__ b1, const float* __restrict__ b2,
    const float* __restrict__ b3, const float* __restrict__ W4,
    const float* __restrict__ b4, const _Float16* __restrict__ ws,
    float* __restrict__ out) {
  __shared__ alignas(16) _Float16 xAhi[4][16][XPAD];
  __shared__ alignas(16) _Float16 xAlo[4][16][XPAD];
  __shared__ alignas(16) _Float16 S1[16][SPAD];
  __shared__ alignas(16) _Float16 S2[16][SPAD];
  __shared__ alignas(16) _Float16 S3[16][SPAD];

  const int tid = threadIdx.x;
  const int wave = tid >> 6;
  const int lane = tid & 63;
  const int n16 = lane & 15;
  const int kg = lane >> 4;
  const int wb = blockIdx.x << 4;
  const int nn = (wave << 4) + n16;

  const _Float16* w1h = ws + W1HI + nn * KP;
  const _Float16* w1l = ws + W1LO + nn * KP;
  const _Float16* w2l = ws + W2LO + nn * NH;
  const _Float16* w3l = ws + W3LO + nn * NH;

  const float bb1 = b1[nn], bb2 = b2[nn], bb3 = b3[nn];

  // Register-resident hi planes of W2/W3 (64 VGPRs), pinned so the RA
  // cannot sink the loads back into the t-loop.
  f4 w2hi_f[8], w3hi_f[8];
  {
    const float* w2h = (const float*)(ws + W2HI + nn * NH);
    const float* w3h = (const float*)(ws + W3HI + nn * NH);
#pragma unroll
    for (int kt = 0; kt < 8; ++kt) {
      w2hi_f[kt] = *(const f4*)(w2h + kt * 16 + kg * 4);
      w3hi_f[kt] = *(const f4*)(w3h + kt * 16 + kg * 4);
    }
#pragma unroll
    for (int kt = 0; kt < 8; ++kt) {
      pin4(w2hi_f[kt]);
      pin4(w3hi_f[kt]);
    }
  }

  // Layer 4 lane roles.
  const int j4 = lane >> 5;
  const int ks4 = (lane & 31) << 3;
  const float* w4p = W4 + j4 * NH + ks4;
  const float bb4 = b4[j4];

  float mem1[4] = {0.f, 0.f, 0.f, 0.f};
  float mem2[4] = {0.f, 0.f, 0.f, 0.f};
  float mem3[4] = {0.f, 0.f, 0.f, 0.f};
  float mem4 = 0.f;

  for (int t = 0; t < TSTEPS; ++t) {
    const int ph = t & 3;
    if (ph == 0) {
      for (unsigned e = (unsigned)tid; e < 16u * KP; e += 1024u) {
        unsigned m = e / KP, i = e % KP;
        f4 v = {0.f, 0.f, 0.f, 0.f};
        if (i < NIN)
          v = __builtin_nontemporal_load(
              (const f4*)(x + ((size_t)(wb + m) * NIN + i) * TSTEPS + t));
#pragma unroll
        for (int s = 0; s < 4; ++s) {
          float f = v[s];
          _Float16 h = (_Float16)f;
          xAhi[s][m][i] = h;
          xAlo[s][m][i] = (_Float16)((f - (float)h) * LO_SCALE);
        }
      }
      lds_barrier();
    }

    // ---------------- layer 1 ----------------
    // W1 loads first, then W2lo prefetch: W1's vmcnt wait leaves the 8 W2lo
    // loads outstanding across the S1 barrier into layer 2's hi phase.
    h8 wh[3], wl1[3];
#pragma unroll
    for (int kt = 0; kt < 3; ++kt) {
      wh[kt] = *(const h8*)(w1h + kt * 32 + kg * 8);
      wl1[kt] = *(const h8*)(w1l + kt * 32 + kg * 8);
    }
    h8 wl2[8];
#pragma unroll
    for (int kt = 0; kt < 8; ++kt)
      wl2[kt] = *(const h8*)(w2l + kt * 32 + kg * 8);

    f4 aH = {0.f, 0.f, 0.f, 0.f};
    f4 aL = {0.f, 0.f, 0.f, 0.f};
#pragma unroll
    for (int kt = 0; kt < 3; ++kt) {
      const int ko = kt * 32 + kg * 8;
      h8 ahi = *(const h8*)&xAhi[ph][n16][ko];
      h8 alo = *(const h8*)&xAlo[ph][n16][ko];
      aH = __builtin_amdgcn_mfma_f32_16x16x32_f16(ahi, wh[kt], aH, 0, 0, 0);
      aL = __builtin_amdgcn_mfma_f32_16x16x32_f16(alo, wh[kt], aL, 0, 0, 0);
      aL = __builtin_amdgcn_mfma_f32_16x16x32_f16(ahi, wl1[kt], aL, 0, 0, 0);
    }
#pragma unroll
    for (int r = 0; r < 4; ++r) {
      float cur = __fadd_rn(__fadd_rn(aH[r], __fmul_rn(aL[r], LO_INV)), bb1);
      float mo = mem1[r];
      float mn = __fsub_rn(__fadd_rn(__fmul_rn(0.95f, mo), cur),
                           (mo > 1.0f) ? 1.0f : 0.0f);
      mem1[r] = mn;
      S1[kg * 4 + r][nn] = (mn > 1.0f) ? (_Float16)1.0f : (_Float16)0.0f;
    }
    lds_barrier();

    // ---------------- layer 2 ----------------
    // Hi phase: register-only MFMAs run while wl2 loads land.
    aH = (f4){0.f, 0.f, 0.f, 0.f};
    aL = (f4){0.f, 0.f, 0.f, 0.f};
#pragma unroll
    for (int kt = 0; kt < 8; ++kt) {
      h8 a = *(const h8*)&S1[n16][kt * 32 + kg * 8];
      aH = __builtin_amdgcn_mfma_f32_16x16x32_f16(
          a, __builtin_bit_cast(h8, w2hi_f[kt]), aH, 0, 0, 0);
    }
#pragma unroll
    for (int kt = 0; kt < 8; ++kt) {
      h8 a = *(const h8*)&S1[n16][kt * 32 + kg * 8];
      aL = __builtin_amdgcn_mfma_f32_16x16x32_f16(a, wl2[kt], aL, 0, 0, 0);
    }
    // Prefetch W3lo: outstanding across the S2 barrier into layer 3.
    h8 wl3[8];
#pragma unroll
    for (int kt = 0; kt < 8; ++kt)
      wl3[kt] = *(const h8*)(w3l + kt * 32 + kg * 8);
#pragma unroll
    for (int r = 0; r < 4; ++r) {
      float cur = __fadd_rn(__fadd_rn(aH[r], __fmul_rn(aL[r], LO_INV)), bb2);
      float mo = mem2[r];
      float mn = __fsub_rn(__fadd_rn(__fmul_rn(0.95f, mo), cur),
                           (mo > 1.0f) ? 1.0f : 0.0f);
      mem2[r] = mn;
      S2[kg * 4 + r][nn] = (mn > 1.0f) ? (_Float16)1.0f : (_Float16)0.0f;
    }
    lds_barrier();

    // ---------------- layer 3 ----------------
    aH = (f4){0.f, 0.f, 0.f, 0.f};
    aL = (f4){0.f, 0.f, 0.f, 0.f};
#pragma unroll
    for (int kt = 0; kt < 8; ++kt) {
      h8 a = *(const h8*)&S2[n16][kt * 32 + kg * 8];
      aH = __builtin_amdgcn_mfma_f32_16x16x32_f16(
          a, __builtin_bit_cast(h8, w3hi_f[kt]), aH, 0, 0, 0);
    }
#pragma unroll
    for (int kt = 0; kt < 8; ++kt) {
      h8 a = *(const h8*)&S2[n16][kt * 32 + kg * 8];
      aL = __builtin_amdgcn_mfma_f32_16x16x32_f16(a, wl3[kt], aL, 0, 0, 0);
    }
    // Prefetch W4 row: outstanding across the S3 barrier.
    f4 w4a = *(const f4*)(w4p);
    f4 w4b = *(const f4*)(w4p + 4);
#pragma unroll
    for (int r = 0; r < 4; ++r) {
      float cur = __fadd_rn(__fadd_rn(aH[r], __fmul_rn(aL[r], LO_INV)), bb3);
      float mo = mem3[r];
      float mn = __fsub_rn(__fadd_rn(__fmul_rn(0.95f, mo), cur),
                           (mo > 1.0f) ? 1.0f : 0.0f);
      mem3[r] = mn;
      S3[kg * 4 + r][nn] = (mn > 1.0f) ? (_Float16)1.0f : (_Float16)0.0f;
    }
    lds_barrier();

    // ---------------- layer 4 ----------------
    {
      h8 s = *(const h8*)&S3[wave][ks4];
      float p = 0.0f;
#pragma unroll
      for (int u = 0; u < 4; ++u)
        p = __fadd_rn(p, __fmul_rn((float)s[u], w4a[u]));
#pragma unroll
      for (int u = 0; u < 4; ++u)
        p = __fadd_rn(p, __fmul_rn((float)s[4 + u], w4b[u]));
#pragma unroll
      for (int msk = 1; msk <= 16; msk <<= 1)
        p = __fadd_rn(p, __shfl_xor(p, msk));
      float cur = __fadd_rn(p, bb4);
      float mo = mem4;
      float mn = __fsub_rn(__fadd_rn(__fmul_rn(0.95f, mo), cur),
                           (mo > 1.0f) ? 1.0f : 0.0f);
      mem4 = mn;
      if ((lane & 31) == 0)
        __builtin_nontemporal_store(
            (mn > 1.0f) ? 1.0f : 0.0f,
            out + (size_t)t * (BATCH * 2) + (size_t)(wb + wave) * 2 + j4);
    }
  }
}

extern "C" void kernel_launch(void* const* d_in, const int* in_sizes, int n_in,
                              void* d_out, int out_size, void* d_ws,
                              size_t ws_size, hipStream_t stream) {
  const float* x  = (const float*)d_in[0];
  const float* W1 = (const float*)d_in[1];
  const float* b1 = (const float*)d_in[2];
  const float* W2 = (const float*)d_in[3];
  const float* b2 = (const float*)d_in[4];
  const float* W3 = (const float*)d_in[5];
  const float* b3 = (const float*)d_in[6];
  const float* W4 = (const float*)d_in[7];
  const float* b4 = (const float*)d_in[8];
  float* out = (float*)d_out;
  _Float16* ws = (_Float16*)d_ws;

  hipLaunchKernelGGL(prep_kernel, dim3(608), dim3(256), 0, stream,
                     W1, W2, W3, ws);
  hipLaunchKernelGGL(snn_kernel, dim3(BATCH / 16), dim3(1024), 0, stream,
                     x, b1, b2, b3, W4, b4, ws, out);
}

// Round 5
// 2510.397 us; speedup vs baseline: 1.2112x; 1.2112x over previous
//
#include <hip/hip_runtime.h>
#include <cstddef>

// SNN: 4-layer LIF net, T=200 sequential steps, batch 4096.
// R5: the per-CU weight stream (608 KB/step through L2/L3 at ~18 B/cyc = 33K
// cyc/step) is the wall. Fixes:
//  (1) amdgpu_waves_per_eu(4,4): R2-R4's launch_bounds minimum let the RA
//      target 8 waves/EU (64-VGPR budget) and spill the "resident" planes to
//      scratch. Pinning 4 waves/EU gives a real 128-VGPR budget.
//  (2) W1hi/W1lo live in LDS (106 KB, stride 104 = conflict-free b128) —
//      residency the RA cannot undo. Layer 1 is fully LDS-fed.
//  (3) W2hi/W3hi in registers (64 VGPRs, pinned).
//  Streamed per step: W2lo+W3lo = 256 KB/CU (was 608), prefetched in halves
//  across vmcnt-transparent lds_barriers under register-only hi phases.
// Numerics bitwise identical to R1-R4 (absmax 0): MFMA order unchanged.
//
// ws layout (_Float16 units): W1hi[256*96] W1lo[256*96] W2hi[256*256]
// W2lo[..] W3hi[..] W3lo[..]  -> 622,592 bytes.

#define BATCH 4096
#define TSTEPS 200
#define NIN 80
#define KP 96
#define NH 256
#define XPAD 104
#define SPAD 264
#define WP1 104   // W1 LDS row stride (halves): 52 words -> 2-way max on b128

#define W1HI 0
#define W1LO 24576
#define W2HI 49152
#define W2LO 114688
#define W3HI 180224
#define W3LO 245760

#define LO_SCALE 2048.0f
#define LO_INV 4.8828125e-4f

typedef _Float16 h8 __attribute__((ext_vector_type(8)));
typedef float f4 __attribute__((ext_vector_type(4)));

// LDS-only barrier: wait lgkmcnt(0), do NOT drain vmcnt.
// simm16 0xC07F: vmcnt=63 (no wait), expcnt=7 (no wait), lgkmcnt=0.
__device__ __forceinline__ void lds_barrier() {
  __builtin_amdgcn_s_waitcnt(0xC07F);
  __builtin_amdgcn_s_barrier();
}

// Register pin: opaque asm output — cannot be rematerialized or sunk.
__device__ __forceinline__ void pin4(f4& v) { asm volatile("" : "+v"(v)); }

__global__ __launch_bounds__(256) void prep_kernel(
    const float* __restrict__ W1, const float* __restrict__ W2,
    const float* __restrict__ W3, _Float16* __restrict__ ws) {
  unsigned id = blockIdx.x * 256u + threadIdx.x;
  if (id >= 24576u + 65536u + 65536u) return;
  float v;
  unsigned off;
  _Float16 *hi, *lo;
  if (id < 24576u) {
    unsigned n = id / KP, k = id % KP;
    v = (k < NIN) ? W1[n * NIN + k] : 0.0f;
    hi = ws + W1HI; lo = ws + W1LO; off = id;
  } else if (id < 90112u) {
    off = id - 24576u; v = W2[off];
    hi = ws + W2HI; lo = ws + W2LO;
  } else {
    off = id - 90112u; v = W3[off];
    hi = ws + W3HI; lo = ws + W3LO;
  }
  _Float16 h = (_Float16)v;
  float r = (v - (float)h) * LO_SCALE;
  hi[off] = h;
  lo[off] = (_Float16)r;
}

__global__ __attribute__((amdgpu_waves_per_eu(4, 4)))
__launch_bounds__(1024) void snn_kernel(
    const float* __restrict__ x,
    const float* __restrict__ b1, const float* __restrict__ b2,
    const float* __restrict__ b3, const float* __restrict__ W4,
    const float* __restrict__ b4, const _Float16* __restrict__ ws,
    float* __restrict__ out) {
  // LDS: W1 planes 106,496 + xA 26,624 + S 25,344 = 158,464 B (<= 160 KiB).
  __shared__ alignas(16) _Float16 Wh1[256][WP1];
  __shared__ alignas(16) _Float16 Wl1[256][WP1];
  __shared__ alignas(16) _Float16 xAhi[4][16][XPAD];
  __shared__ alignas(16) _Float16 xAlo[4][16][XPAD];
  __shared__ alignas(16) _Float16 S1[16][SPAD];
  __shared__ alignas(16) _Float16 S2[16][SPAD];
  __shared__ alignas(16) _Float16 S3[16][SPAD];

  const int tid = threadIdx.x;
  const int wave = tid >> 6;
  const int lane = tid & 63;
  const int n16 = lane & 15;
  const int kg = lane >> 4;
  const int wb = blockIdx.x << 4;
  const int nn = (wave << 4) + n16;

  // Copy W1 planes into LDS once (96 KB from L2; 3 iterations/thread).
  for (int c = tid; c < 3072; c += 1024) {
    int row = c / 12, w = c % 12;
    *(h8*)&Wh1[row][w * 8] = *(const h8*)(ws + W1HI + row * KP + w * 8);
    *(h8*)&Wl1[row][w * 8] = *(const h8*)(ws + W1LO + row * KP + w * 8);
  }

  const _Float16* w2l = ws + W2LO + nn * NH;
  const _Float16* w3l = ws + W3LO + nn * NH;

  const float bb1 = b1[nn], bb2 = b2[nn], bb3 = b3[nn];

  // Register-resident hi planes of W2/W3 (64 VGPRs), pinned. With
  // waves_per_eu(4,4) the 128-VGPR budget makes this genuinely hold.
  f4 w2hi_f[8], w3hi_f[8];
  {
    const float* w2h = (const float*)(ws + W2HI + nn * NH);
    const float* w3h = (const float*)(ws + W3HI + nn * NH);
#pragma unroll
    for (int kt = 0; kt < 8; ++kt) {
      w2hi_f[kt] = *(const f4*)(w2h + kt * 16 + kg * 4);
      w3hi_f[kt] = *(const f4*)(w3h + kt * 16 + kg * 4);
    }
#pragma unroll
    for (int kt = 0; kt < 8; ++kt) {
      pin4(w2hi_f[kt]);
      pin4(w3hi_f[kt]);
    }
  }

  // Layer 4 lane roles.
  const int j4 = lane >> 5;
  const int ks4 = (lane & 31) << 3;
  const float* w4p = W4 + j4 * NH + ks4;
  const float bb4 = b4[j4];

  float mem1[4] = {0.f, 0.f, 0.f, 0.f};
  float mem2[4] = {0.f, 0.f, 0.f, 0.f};
  float mem3[4] = {0.f, 0.f, 0.f, 0.f};
  float mem4 = 0.f;

  for (int t = 0; t < TSTEPS; ++t) {
    const int ph = t & 3;
    if (ph == 0) {
      for (unsigned e = (unsigned)tid; e < 16u * KP; e += 1024u) {
        unsigned m = e / KP, i = e % KP;
        f4 v = {0.f, 0.f, 0.f, 0.f};
        if (i < NIN)
          v = __builtin_nontemporal_load(
              (const f4*)(x + ((size_t)(wb + m) * NIN + i) * TSTEPS + t));
#pragma unroll
        for (int s = 0; s < 4; ++s) {
          float f = v[s];
          _Float16 h = (_Float16)f;
          xAhi[s][m][i] = h;
          xAlo[s][m][i] = (_Float16)((f - (float)h) * LO_SCALE);
        }
      }
      lds_barrier();  // also covers the one-time W1 LDS fill at t=0
    }

    // ---------------- layer 1 : fully LDS-fed ----------------
    // Prefetch first half of W2lo; it stays outstanding across the S1
    // barrier (lds_barrier leaves vmcnt alone).
    h8 wl2a[4];
#pragma unroll
    for (int q = 0; q < 4; ++q)
      wl2a[q] = *(const h8*)(w2l + q * 32 + kg * 8);

    f4 aH = {0.f, 0.f, 0.f, 0.f};
    f4 aL = {0.f, 0.f, 0.f, 0.f};
#pragma unroll
    for (int kt = 0; kt < 3; ++kt) {
      const int ko = kt * 32 + kg * 8;
      h8 ahi = *(const h8*)&xAhi[ph][n16][ko];
      h8 alo = *(const h8*)&xAlo[ph][n16][ko];
      h8 wh = *(const h8*)&Wh1[nn][ko];
      h8 wl = *(const h8*)&Wl1[nn][ko];
      aH = __builtin_amdgcn_mfma_f32_16x16x32_f16(ahi, wh, aH, 0, 0, 0);
      aL = __builtin_amdgcn_mfma_f32_16x16x32_f16(alo, wh, aL, 0, 0, 0);
      aL = __builtin_amdgcn_mfma_f32_16x16x32_f16(ahi, wl, aL, 0, 0, 0);
    }
#pragma unroll
    for (int r = 0; r < 4; ++r) {
      float cur = __fadd_rn(__fadd_rn(aH[r], __fmul_rn(aL[r], LO_INV)), bb1);
      float mo = mem1[r];
      float mn = __fsub_rn(__fadd_rn(__fmul_rn(0.95f, mo), cur),
                           (mo > 1.0f) ? 1.0f : 0.0f);
      mem1[r] = mn;
      S1[kg * 4 + r][nn] = (mn > 1.0f) ? (_Float16)1.0f : (_Float16)0.0f;
    }
    lds_barrier();

    // ---------------- layer 2 : hi resident, lo streamed ----------------
    h8 wl2b[4];
#pragma unroll
    for (int q = 0; q < 4; ++q)
      wl2b[q] = *(const h8*)(w2l + (4 + q) * 32 + kg * 8);

    // Hi phase: register-only MFMAs run while wl2 loads land.
    aH = (f4){0.f, 0.f, 0.f, 0.f};
    aL = (f4){0.f, 0.f, 0.f, 0.f};
#pragma unroll
    for (int kt = 0; kt < 8; ++kt) {
      h8 a = *(const h8*)&S1[n16][kt * 32 + kg * 8];
      aH = __builtin_amdgcn_mfma_f32_16x16x32_f16(
          a, __builtin_bit_cast(h8, w2hi_f[kt]), aH, 0, 0, 0);
    }
#pragma unroll
    for (int q = 0; q < 4; ++q) {
      h8 a = *(const h8*)&S1[n16][q * 32 + kg * 8];
      aL = __builtin_amdgcn_mfma_f32_16x16x32_f16(a, wl2a[q], aL, 0, 0, 0);
    }
    h8 wl3a[4];
#pragma unroll
    for (int q = 0; q < 4; ++q)
      wl3a[q] = *(const h8*)(w3l + q * 32 + kg * 8);
#pragma unroll
    for (int q = 0; q < 4; ++q) {
      h8 a = *(const h8*)&S1[n16][(4 + q) * 32 + kg * 8];
      aL = __builtin_amdgcn_mfma_f32_16x16x32_f16(a, wl2b[q], aL, 0, 0, 0);
    }
#pragma unroll
    for (int r = 0; r < 4; ++r) {
      float cur = __fadd_rn(__fadd_rn(aH[r], __fmul_rn(aL[r], LO_INV)), bb2);
      float mo = mem2[r];
      float mn = __fsub_rn(__fadd_rn(__fmul_rn(0.95f, mo), cur),
                           (mo > 1.0f) ? 1.0f : 0.0f);
      mem2[r] = mn;
      S2[kg * 4 + r][nn] = (mn > 1.0f) ? (_Float16)1.0f : (_Float16)0.0f;
    }
    lds_barrier();

    // ---------------- layer 3 : hi resident, lo streamed ----------------
    h8 wl3b[4];
#pragma unroll
    for (int q = 0; q < 4; ++q)
      wl3b[q] = *(const h8*)(w3l + (4 + q) * 32 + kg * 8);

    aH = (f4){0.f, 0.f, 0.f, 0.f};
    aL = (f4){0.f, 0.f, 0.f, 0.f};
#pragma unroll
    for (int kt = 0; kt < 8; ++kt) {
      h8 a = *(const h8*)&S2[n16][kt * 32 + kg * 8];
      aH = __builtin_amdgcn_mfma_f32_16x16x32_f16(
          a, __builtin_bit_cast(h8, w3hi_f[kt]), aH, 0, 0, 0);
    }
#pragma unroll
    for (int q = 0; q < 4; ++q) {
      h8 a = *(const h8*)&S2[n16][q * 32 + kg * 8];
      aL = __builtin_amdgcn_mfma_f32_16x16x32_f16(a, wl3a[q], aL, 0, 0, 0);
    }
    // Prefetch W4 row (L1-hot): outstanding across the S3 barrier.
    f4 w4a = *(const f4*)(w4p);
    f4 w4b = *(const f4*)(w4p + 4);
#pragma unroll
    for (int q = 0; q < 4; ++q) {
      h8 a = *(const h8*)&S2[n16][(4 + q) * 32 + kg * 8];
      aL = __builtin_amdgcn_mfma_f32_16x16x32_f16(a, wl3b[q], aL, 0, 0, 0);
    }
#pragma unroll
    for (int r = 0; r < 4; ++r) {
      float cur = __fadd_rn(__fadd_rn(aH[r], __fmul_rn(aL[r], LO_INV)), bb3);
      float mo = mem3[r];
      float mn = __fsub_rn(__fadd_rn(__fmul_rn(0.95f, mo), cur),
                           (mo > 1.0f) ? 1.0f : 0.0f);
      mem3[r] = mn;
      S3[kg * 4 + r][nn] = (mn > 1.0f) ? (_Float16)1.0f : (_Float16)0.0f;
    }
    lds_barrier();

    // ---------------- layer 4 : VALU dot + butterfly ----------------
    {
      h8 s = *(const h8*)&S3[wave][ks4];
      float p = 0.0f;
#pragma unroll
      for (int u = 0; u < 4; ++u)
        p = __fadd_rn(p, __fmul_rn((float)s[u], w4a[u]));
#pragma unroll
      for (int u = 0; u < 4; ++u)
        p = __fadd_rn(p, __fmul_rn((float)s[4 + u], w4b[u]));
#pragma unroll
      for (int msk = 1; msk <= 16; msk <<= 1)
        p = __fadd_rn(p, __shfl_xor(p, msk));
      float cur = __fadd_rn(p, bb4);
      float mo = mem4;
      float mn = __fsub_rn(__fadd_rn(__fmul_rn(0.95f, mo), cur),
                           (mo > 1.0f) ? 1.0f : 0.0f);
      mem4 = mn;
      if ((lane & 31) == 0)
        __builtin_nontemporal_store(
            (mn > 1.0f) ? 1.0f : 0.0f,
            out + (size_t)t * (BATCH * 2) + (size_t)(wb + wave) * 2 + j4);
    }
  }
}

extern "C" void kernel_launch(void* const* d_in, const int* in_sizes, int n_in,
                              void* d_out, int out_size, void* d_ws,
                              size_t ws_size, hipStream_t stream) {
  const float* x  = (const float*)d_in[0];
  const float* W1 = (const float*)d_in[1];
  const float* b1 = (const float*)d_in[2];
  const float* W2 = (const float*)d_in[3];
  const float* b2 = (const float*)d_in[4];
  const float* W3 = (const float*)d_in[5];
  const float* b3 = (const float*)d_in[6];
  const float* W4 = (const float*)d_in[7];
  const float* b4 = (const float*)d_in[8];
  float* out = (float*)d_out;
  _Float16* ws = (_Float16*)d_ws;

  hipLaunchKernelGGL(prep_kernel, dim3(608), dim3(256), 0, stream,
                     W1, W2, W3, ws);
  hipLaunchKernelGGL(snn_kernel, dim3(BATCH / 16), dim3(1024), 0, stream,
                     x, b1, b2, b3, W4, b4, ws, out);
}